// Round 1
// baseline (2175.868 us; speedup 1.0000x reference)
//
#include <hip/hip_runtime.h>
#include <hip/hip_bf16.h>
#include <math.h>

// Problem constants
#define BATCH 2
#define SLEN  2048
#define DIN   1024
#define DMODEL 1024
#define NHEAD 16
#define HD    64
#define E3    3072   // 3*DMODEL, row width of qkv

// ---------------- GEMM: C[M,N] = A[M,K] * B[N,K]^T + bias[N] ----------------
// Both A and B are row-major with K contiguous (B-transposed GEMM).
// 64x64 tile, BK=32, 256 threads, 4x4 per thread. LDS stored [k][m] so the
// inner-loop fragment reads are float4 (ds_read_b128).
#define GT 64
#define GBK 32
#define GSTR 68  // 64 + 4 pad, keeps float4 alignment, staggers banks

__global__ __launch_bounds__(256) void gemm_bt_bias(
    const float* __restrict__ A, const float* __restrict__ Bm,
    const float* __restrict__ bias, float* __restrict__ C,
    int M, int N, int K)
{
    __shared__ float As[GBK][GSTR];
    __shared__ float Bs[GBK][GSTR];

    const int t  = threadIdx.x;
    const int tx = t & 15;        // 0..15 -> n
    const int ty = t >> 4;        // 0..15 -> m
    const int m0 = blockIdx.y * GT;
    const int n0 = blockIdx.x * GT;

    const int lr = t >> 3;        // 0..31 : tile row
    const int lc = (t & 7) * 4;   // 0,4,...,28 : k offset

    float acc[4][4];
#pragma unroll
    for (int i = 0; i < 4; ++i)
#pragma unroll
        for (int j = 0; j < 4; ++j) acc[i][j] = 0.f;

    for (int k0 = 0; k0 < K; k0 += GBK) {
        // stage global -> regs
        const float4 a0 = *(const float4*)&A[(size_t)(m0 + lr) * K + k0 + lc];
        const float4 a1 = *(const float4*)&A[(size_t)(m0 + lr + 32) * K + k0 + lc];
        const float4 b0 = *(const float4*)&Bm[(size_t)(n0 + lr) * K + k0 + lc];
        const float4 b1 = *(const float4*)&Bm[(size_t)(n0 + lr + 32) * K + k0 + lc];
        __syncthreads();  // previous iteration finished reading LDS
        // store transposed: As[k][m]
        As[lc+0][lr] = a0.x; As[lc+1][lr] = a0.y; As[lc+2][lr] = a0.z; As[lc+3][lr] = a0.w;
        As[lc+0][lr+32] = a1.x; As[lc+1][lr+32] = a1.y; As[lc+2][lr+32] = a1.z; As[lc+3][lr+32] = a1.w;
        Bs[lc+0][lr] = b0.x; Bs[lc+1][lr] = b0.y; Bs[lc+2][lr] = b0.z; Bs[lc+3][lr] = b0.w;
        Bs[lc+0][lr+32] = b1.x; Bs[lc+1][lr+32] = b1.y; Bs[lc+2][lr+32] = b1.z; Bs[lc+3][lr+32] = b1.w;
        __syncthreads();
#pragma unroll
        for (int kk = 0; kk < GBK; ++kk) {
            const float4 av = *(const float4*)&As[kk][ty * 4];
            const float4 bv = *(const float4*)&Bs[kk][tx * 4];
            const float a[4] = {av.x, av.y, av.z, av.w};
            const float b[4] = {bv.x, bv.y, bv.z, bv.w};
#pragma unroll
            for (int i = 0; i < 4; ++i)
#pragma unroll
                for (int j = 0; j < 4; ++j)
                    acc[i][j] = fmaf(a[i], b[j], acc[i][j]);
        }
    }

    const float4 bi = *(const float4*)&bias[n0 + tx * 4];
#pragma unroll
    for (int i = 0; i < 4; ++i) {
        float4 o;
        o.x = acc[i][0] + bi.x;
        o.y = acc[i][1] + bi.y;
        o.z = acc[i][2] + bi.z;
        o.w = acc[i][3] + bi.w;
        *(float4*)&C[(size_t)(m0 + ty * 4 + i) * N + n0 + tx * 4] = o;
    }
}

// ---------------- Flash attention (fp32) ----------------
// qkv layout: [B, S, 3072]; head h: Q at h*192+0, K at h*192+64, V at h*192+128.
// One block = 16 waves = 16 queries of one (b,h). Iterate 64-key chunks:
// lane j owns key j of the chunk; per-lane O-partials (64 regs) accumulate
// p_j * V[j][:]; online softmax state (m,l) per wave; final cross-lane
// transpose-reduce puts O[d] on lane d.
#define QPB 16
#define CH  64
#define KSTR2 68

__device__ __forceinline__ float wave_max64(float v) {
#pragma unroll
    for (int off = 32; off > 0; off >>= 1) v = fmaxf(v, __shfl_xor(v, off));
    return v;
}
__device__ __forceinline__ float wave_sum64(float v) {
#pragma unroll
    for (int off = 32; off > 0; off >>= 1) v += __shfl_xor(v, off);
    return v;
}

__global__ __launch_bounds__(1024) void attn_flash_f32(
    const float* __restrict__ qkv, float* __restrict__ vals)
{
    __shared__ float Qs[QPB][KSTR2];
    __shared__ float Ks[CH][KSTR2];
    __shared__ float Vs[CH][KSTR2];

    const int t    = threadIdx.x;
    const int lane = t & 63;
    const int wave = t >> 6;               // 0..15, one query per wave
    const int bh   = blockIdx.y;           // 0..31
    const int b    = bh >> 4;
    const int h    = bh & 15;
    const int q0   = blockIdx.x * QPB;

    const size_t base = (size_t)b * SLEN * E3;
    const int qoff = h * 192;

    // Load Q tile (16 queries x 64 dims) once
    if (t < 256) {
        const int r = t >> 4;
        const int i = (t & 15) * 4;
        const float4 q4 = *(const float4*)&qkv[base + (size_t)(q0 + r) * E3 + qoff + i];
        Qs[r][i] = q4.x; Qs[r][i+1] = q4.y; Qs[r][i+2] = q4.z; Qs[r][i+3] = q4.w;
    }

    float m = -INFINITY, l = 0.f;
    float O[HD];
#pragma unroll
    for (int d = 0; d < HD; ++d) O[d] = 0.f;

    const int lrow = t >> 4;         // 0..63
    const int lcol = (t & 15) * 4;   // 0..60

    for (int c = 0; c < SLEN / CH; ++c) {
        __syncthreads();  // previous chunk fully consumed (also covers Q store)
        {
            const size_t grow = base + (size_t)(c * CH + lrow) * E3 + qoff;
            const float4 k4 = *(const float4*)&qkv[grow + 64 + lcol];
            const float4 v4 = *(const float4*)&qkv[grow + 128 + lcol];
            Ks[lrow][lcol] = k4.x; Ks[lrow][lcol+1] = k4.y; Ks[lrow][lcol+2] = k4.z; Ks[lrow][lcol+3] = k4.w;
            Vs[lrow][lcol] = v4.x; Vs[lrow][lcol+1] = v4.y; Vs[lrow][lcol+2] = v4.z; Vs[lrow][lcol+3] = v4.w;
        }
        __syncthreads();

        // score for key (c*CH + lane)
        float s = 0.f;
#pragma unroll
        for (int i = 0; i < HD; i += 4) {
            const float4 q4 = *(const float4*)&Qs[wave][i];   // broadcast
            const float4 k4 = *(const float4*)&Ks[lane][i];
            s = fmaf(q4.x, k4.x, s);
            s = fmaf(q4.y, k4.y, s);
            s = fmaf(q4.z, k4.z, s);
            s = fmaf(q4.w, k4.w, s);
        }
        s *= 0.125f;  // 1/sqrt(64)

        const float cm    = wave_max64(s);
        const float m_new = fmaxf(m, cm);
        const float alpha = __expf(m - m_new);   // first chunk: exp(-inf)=0
        const float p     = __expf(s - m_new);
        const float ps    = wave_sum64(p);
        l = l * alpha + ps;
        m = m_new;

#pragma unroll
        for (int i = 0; i < HD; i += 4) {
            const float4 v4 = *(const float4*)&Vs[lane][i];
            O[i+0] = fmaf(p, v4.x, O[i+0] * alpha);
            O[i+1] = fmaf(p, v4.y, O[i+1] * alpha);
            O[i+2] = fmaf(p, v4.z, O[i+2] * alpha);
            O[i+3] = fmaf(p, v4.w, O[i+3] * alpha);
        }
    }

    // O[d] (summed over lanes) -> lane d, normalize, store
    float out_val = 0.f;
#pragma unroll
    for (int d = 0; d < HD; ++d) {
        const float v = wave_sum64(O[d]);
        if (lane == d) out_val = v;
    }
    const int q = q0 + wave;
    vals[(size_t)(b * SLEN + q) * DMODEL + h * HD + lane] = out_val / l;
}

// ---------------- launch ----------------
extern "C" void kernel_launch(void* const* d_in, const int* in_sizes, int n_in,
                              void* d_out, int out_size, void* d_ws, size_t ws_size,
                              hipStream_t stream) {
    const float* x     = (const float*)d_in[0];  // [B,S,DIN]
    const float* w_qkv = (const float*)d_in[1];  // [3D, DIN]
    const float* b_qkv = (const float*)d_in[2];  // [3D]
    const float* w_o   = (const float*)d_in[3];  // [D, D]
    const float* b_o   = (const float*)d_in[4];  // [D]
    float* out = (float*)d_out;                  // [B,S,D]

    float* qkv  = (float*)d_ws;                            // B*S*3072 fp32 = 50.3 MB
    float* vals = qkv + (size_t)BATCH * SLEN * E3;         // B*S*1024 fp32 = 16.8 MB

    const int M = BATCH * SLEN;  // 4096

    // 1) qkv = x @ w_qkv^T + b_qkv   [4096 x 3072]
    {
        dim3 grid(E3 / GT, M / GT);
        gemm_bt_bias<<<grid, 256, 0, stream>>>(x, w_qkv, b_qkv, qkv, M, E3, DIN);
    }
    // 2) attention -> vals [B,S,D]
    {
        dim3 grid(SLEN / QPB, BATCH * NHEAD);
        attn_flash_f32<<<grid, 1024, 0, stream>>>(qkv, vals);
    }
    // 3) out = vals @ w_o^T + b_o    [4096 x 1024]
    {
        dim3 grid(DMODEL / GT, M / GT);
        gemm_bt_bias<<<grid, 256, 0, stream>>>(vals, w_o, b_o, out, M, DMODEL, DIN);
    }
}

// Round 2
// 682.170 us; speedup vs baseline: 3.1896x; 3.1896x over previous
//
#include <hip/hip_runtime.h>
#include <hip/hip_bf16.h>
#include <math.h>

// Problem constants
#define BATCH 2
#define SLEN  2048
#define DIN   1024
#define DMODEL 1024
#define NHEAD 16
#define HD    64
#define E3    3072   // 3*DMODEL, row width of qkv

typedef __attribute__((ext_vector_type(8))) __bf16 bf16x8;
typedef __attribute__((ext_vector_type(8))) unsigned short us8;
typedef __attribute__((ext_vector_type(4))) float f32x4;

__device__ __forceinline__ unsigned short bf16rne(float x) {
    unsigned int u = __float_as_uint(x);
    u += 0x7FFFu + ((u >> 16) & 1u);
    return (unsigned short)(u >> 16);
}

__device__ __forceinline__ us8 pack8(float4 a, float4 b) {
    us8 r;
    r[0] = bf16rne(a.x); r[1] = bf16rne(a.y); r[2] = bf16rne(a.z); r[3] = bf16rne(a.w);
    r[4] = bf16rne(b.x); r[5] = bf16rne(b.y); r[6] = bf16rne(b.z); r[7] = bf16rne(b.w);
    return r;
}

// ---------------- GEMM: C[M,N] = A[M,K] * B[N,K]^T + bias[N] (fp32) ----------------
#define GT 64
#define GBK 32
#define GSTR 68

__global__ __launch_bounds__(256) void gemm_bt_bias(
    const float* __restrict__ A, const float* __restrict__ Bm,
    const float* __restrict__ bias, float* __restrict__ C,
    int M, int N, int K)
{
    __shared__ float As[GBK][GSTR];
    __shared__ float Bs[GBK][GSTR];

    const int t  = threadIdx.x;
    const int tx = t & 15;
    const int ty = t >> 4;
    const int m0 = blockIdx.y * GT;
    const int n0 = blockIdx.x * GT;

    const int lr = t >> 3;
    const int lc = (t & 7) * 4;

    float acc[4][4];
#pragma unroll
    for (int i = 0; i < 4; ++i)
#pragma unroll
        for (int j = 0; j < 4; ++j) acc[i][j] = 0.f;

    for (int k0 = 0; k0 < K; k0 += GBK) {
        const float4 a0 = *(const float4*)&A[(size_t)(m0 + lr) * K + k0 + lc];
        const float4 a1 = *(const float4*)&A[(size_t)(m0 + lr + 32) * K + k0 + lc];
        const float4 b0 = *(const float4*)&Bm[(size_t)(n0 + lr) * K + k0 + lc];
        const float4 b1 = *(const float4*)&Bm[(size_t)(n0 + lr + 32) * K + k0 + lc];
        __syncthreads();
        As[lc+0][lr] = a0.x; As[lc+1][lr] = a0.y; As[lc+2][lr] = a0.z; As[lc+3][lr] = a0.w;
        As[lc+0][lr+32] = a1.x; As[lc+1][lr+32] = a1.y; As[lc+2][lr+32] = a1.z; As[lc+3][lr+32] = a1.w;
        Bs[lc+0][lr] = b0.x; Bs[lc+1][lr] = b0.y; Bs[lc+2][lr] = b0.z; Bs[lc+3][lr] = b0.w;
        Bs[lc+0][lr+32] = b1.x; Bs[lc+1][lr+32] = b1.y; Bs[lc+2][lr+32] = b1.z; Bs[lc+3][lr+32] = b1.w;
        __syncthreads();
#pragma unroll
        for (int kk = 0; kk < GBK; ++kk) {
            const float4 av = *(const float4*)&As[kk][ty * 4];
            const float4 bv = *(const float4*)&Bs[kk][tx * 4];
            const float a[4] = {av.x, av.y, av.z, av.w};
            const float b[4] = {bv.x, bv.y, bv.z, bv.w};
#pragma unroll
            for (int i = 0; i < 4; ++i)
#pragma unroll
                for (int j = 0; j < 4; ++j)
                    acc[i][j] = fmaf(a[i], b[j], acc[i][j]);
        }
    }

    const float4 bi = *(const float4*)&bias[n0 + tx * 4];
#pragma unroll
    for (int i = 0; i < 4; ++i) {
        float4 o;
        o.x = acc[i][0] + bi.x;
        o.y = acc[i][1] + bi.y;
        o.z = acc[i][2] + bi.z;
        o.w = acc[i][3] + bi.w;
        *(float4*)&C[(size_t)(m0 + ty * 4 + i) * N + n0 + tx * 4] = o;
    }
}

// ---------------- MFMA flash attention (bf16 compute, fp32 softmax state) ----------------
// Block = 8 waves * 64 = 512 threads; each wave: 16 queries; block: 128 queries of one (b,h).
// Chunk = 64 keys. QK^T and PV via mfma_f32_16x16x32_bf16.
// Layouts (verified m89/m120): A-frag A[m=lane&15][k=quad*8+j]; B-frag B[k=quad*8+j][n=lane&15];
// C/D: row(m)=quad*4+reg, col(n)=lane&15.
#define AW  8
#define ABQ 128   // queries per block
#define ACH 64    // keys per chunk
#define LQ  72    // LDS row stride in bf16 elems (144 B: 16B-aligned, ~2-way banks)

__global__ __launch_bounds__(512, 4) void attn_mfma(
    const float* __restrict__ qkv, float* __restrict__ vals)
{
    __shared__ __align__(16) unsigned short Qs[ABQ][LQ];   // 18432 B
    __shared__ __align__(16) unsigned short Ks[ACH][LQ];   //  9216 B
    __shared__ __align__(16) unsigned short Vt[HD][LQ];    //  9216 B  (Vt[dim][key])
    __shared__ __align__(16) unsigned short Ps[AW][16][LQ];// 18432 B

    const int t    = threadIdx.x;
    const int lane = t & 63;
    const int w    = t >> 6;        // wave 0..7
    const int ml   = lane & 15;
    const int quad = lane >> 4;

    const int bh = blockIdx.y;
    const int b  = bh >> 4;
    const int h  = bh & 15;
    const int q0 = blockIdx.x * ABQ;

    const size_t base = (size_t)b * SLEN * E3;
    const int qoff = h * 192;

    // ---- stage Q (128 q x 64 d) as bf16, once ----
    {
        const int row = t >> 2;
        const int seg = (t & 3) * 16;
        const float* g = &qkv[base + (size_t)(q0 + row) * E3 + qoff + seg];
        const float4 f0 = *(const float4*)(g);
        const float4 f1 = *(const float4*)(g + 4);
        const float4 f2 = *(const float4*)(g + 8);
        const float4 f3 = *(const float4*)(g + 12);
        *(us8*)&Qs[row][seg]     = pack8(f0, f1);
        *(us8*)&Qs[row][seg + 8] = pack8(f2, f3);
    }

    float mrow[4], lrow[4];
    f32x4 O[4];
#pragma unroll
    for (int r = 0; r < 4; ++r) {
        mrow[r] = -INFINITY; lrow[r] = 0.f;
        O[r][0] = 0.f; O[r][1] = 0.f; O[r][2] = 0.f; O[r][3] = 0.f;
    }

    const float C = 0.125f;  // 1/sqrt(HD), folded into exp arguments
    const int krow = t >> 3;        // 0..63 : key within chunk
    const int kseg = (t & 7) * 8;   // 0..56 : dim segment

    for (int c = 0; c < SLEN / ACH; ++c) {
        __syncthreads();   // previous chunk's K/Vt fully consumed (and Q staged, 1st iter)
        {
            const float* gk = &qkv[base + (size_t)(c * ACH + krow) * E3 + qoff + 64 + kseg];
            const float4 k0 = *(const float4*)(gk);
            const float4 k1 = *(const float4*)(gk + 4);
            const float4 v0 = *(const float4*)(gk + 64);
            const float4 v1 = *(const float4*)(gk + 68);
            *(us8*)&Ks[krow][kseg] = pack8(k0, k1);
            // V transposed: Vt[dim][key]
            Vt[kseg + 0][krow] = bf16rne(v0.x);
            Vt[kseg + 1][krow] = bf16rne(v0.y);
            Vt[kseg + 2][krow] = bf16rne(v0.z);
            Vt[kseg + 3][krow] = bf16rne(v0.w);
            Vt[kseg + 4][krow] = bf16rne(v1.x);
            Vt[kseg + 5][krow] = bf16rne(v1.y);
            Vt[kseg + 6][krow] = bf16rne(v1.z);
            Vt[kseg + 7][krow] = bf16rne(v1.w);
        }
        __syncthreads();

        // ---- QK^T: scores for 16 q x 64 k ----
        const bf16x8 aq0 = __builtin_bit_cast(bf16x8, *(const us8*)&Qs[w * 16 + ml][quad * 8]);
        const bf16x8 aq1 = __builtin_bit_cast(bf16x8, *(const us8*)&Qs[w * 16 + ml][32 + quad * 8]);
        f32x4 sc[4];
#pragma unroll
        for (int nt = 0; nt < 4; ++nt) {
            const bf16x8 bk0 = __builtin_bit_cast(bf16x8, *(const us8*)&Ks[nt * 16 + ml][quad * 8]);
            const bf16x8 bk1 = __builtin_bit_cast(bf16x8, *(const us8*)&Ks[nt * 16 + ml][32 + quad * 8]);
            f32x4 z = {0.f, 0.f, 0.f, 0.f};
            z = __builtin_amdgcn_mfma_f32_16x16x32_bf16(aq0, bk0, z, 0, 0, 0);
            z = __builtin_amdgcn_mfma_f32_16x16x32_bf16(aq1, bk1, z, 0, 0, 0);
            sc[nt] = z;
        }

        // ---- online softmax (per reg r: query = quad*4 + r) ----
#pragma unroll
        for (int r = 0; r < 4; ++r) {
            float cm = fmaxf(fmaxf(sc[0][r], sc[1][r]), fmaxf(sc[2][r], sc[3][r]));
            cm = fmaxf(cm, __shfl_xor(cm, 1));
            cm = fmaxf(cm, __shfl_xor(cm, 2));
            cm = fmaxf(cm, __shfl_xor(cm, 4));
            cm = fmaxf(cm, __shfl_xor(cm, 8));
            const float mn = fmaxf(mrow[r], cm);
            const float alpha = __expf((mrow[r] - mn) * C);  // 1st chunk: exp(-inf)=0
            mrow[r] = mn;
            float ps = 0.f;
            unsigned short pb[4];
#pragma unroll
            for (int nt = 0; nt < 4; ++nt) {
                const float p = __expf((sc[nt][r] - mn) * C);
                ps += p;
                pb[nt] = bf16rne(p);
            }
            ps += __shfl_xor(ps, 1);
            ps += __shfl_xor(ps, 2);
            ps += __shfl_xor(ps, 4);
            ps += __shfl_xor(ps, 8);
            lrow[r] = lrow[r] * alpha + ps;
#pragma unroll
            for (int nt = 0; nt < 4; ++nt) {
                O[nt][r] *= alpha;
                Ps[w][quad * 4 + r][nt * 16 + ml] = pb[nt];
            }
        }

        // ---- PV: O += P(16x64) * V(64x64) ---- (Ps is wave-private; lgkmcnt orders it)
        const bf16x8 ap0 = __builtin_bit_cast(bf16x8, *(const us8*)&Ps[w][ml][quad * 8]);
        const bf16x8 ap1 = __builtin_bit_cast(bf16x8, *(const us8*)&Ps[w][ml][32 + quad * 8]);
#pragma unroll
        for (int nt = 0; nt < 4; ++nt) {
            const bf16x8 bv0 = __builtin_bit_cast(bf16x8, *(const us8*)&Vt[nt * 16 + ml][quad * 8]);
            const bf16x8 bv1 = __builtin_bit_cast(bf16x8, *(const us8*)&Vt[nt * 16 + ml][32 + quad * 8]);
            O[nt] = __builtin_amdgcn_mfma_f32_16x16x32_bf16(ap0, bv0, O[nt], 0, 0, 0);
            O[nt] = __builtin_amdgcn_mfma_f32_16x16x32_bf16(ap1, bv1, O[nt], 0, 0, 0);
        }
    }

    // ---- epilogue: normalize and store ----
#pragma unroll
    for (int r = 0; r < 4; ++r) {
        const float rl = 1.0f / lrow[r];
        const int q = q0 + w * 16 + quad * 4 + r;
#pragma unroll
        for (int nt = 0; nt < 4; ++nt) {
            vals[(size_t)(b * SLEN + q) * DMODEL + h * HD + nt * 16 + ml] = O[nt][r] * rl;
        }
    }
}

// ---------------- launch ----------------
extern "C" void kernel_launch(void* const* d_in, const int* in_sizes, int n_in,
                              void* d_out, int out_size, void* d_ws, size_t ws_size,
                              hipStream_t stream) {
    const float* x     = (const float*)d_in[0];
    const float* w_qkv = (const float*)d_in[1];
    const float* b_qkv = (const float*)d_in[2];
    const float* w_o   = (const float*)d_in[3];
    const float* b_o   = (const float*)d_in[4];
    float* out = (float*)d_out;

    float* qkv  = (float*)d_ws;                      // 50.3 MB
    float* vals = qkv + (size_t)BATCH * SLEN * E3;   // 16.8 MB

    const int M = BATCH * SLEN;  // 4096

    // 1) qkv = x @ w_qkv^T + b_qkv
    {
        dim3 grid(E3 / GT, M / GT);
        gemm_bt_bias<<<grid, 256, 0, stream>>>(x, w_qkv, b_qkv, qkv, M, E3, DIN);
    }
    // 2) attention -> vals
    {
        dim3 grid(SLEN / ABQ, BATCH * NHEAD);
        attn_mfma<<<grid, 512, 0, stream>>>(qkv, vals);
    }
    // 3) out = vals @ w_o^T + b_o
    {
        dim3 grid(DMODEL / GT, M / GT);
        gemm_bt_bias<<<grid, 256, 0, stream>>>(vals, w_o, b_o, out, M, DMODEL, DIN);
    }
}

// Round 3
// 371.825 us; speedup vs baseline: 5.8519x; 1.8347x over previous
//
#include <hip/hip_runtime.h>
#include <hip/hip_bf16.h>
#include <math.h>

// Problem constants
#define BATCH 2
#define SLEN  2048
#define DIN   1024
#define DMODEL 1024
#define NHEAD 16
#define HD    64
#define E3    3072   // 3*DMODEL, row width of qkv

typedef unsigned short us;
typedef __attribute__((ext_vector_type(8))) __bf16 bf16x8;
typedef __attribute__((ext_vector_type(8))) unsigned short us8;
typedef __attribute__((ext_vector_type(4))) float f32x4;

__device__ __forceinline__ unsigned short bf16rne(float x) {
    unsigned int u = __float_as_uint(x);
    u += 0x7FFFu + ((u >> 16) & 1u);
    return (unsigned short)(u >> 16);
}
__device__ __forceinline__ float bf16tof(unsigned short h) {
    return __uint_as_float(((unsigned int)h) << 16);
}

// async 16B global->LDS (lane i deposits at ldsbase + i*16)
#define GLL16(g, l)                                                                     \
    __builtin_amdgcn_global_load_lds((const __attribute__((address_space(1))) unsigned int*)(g), \
                                     (__attribute__((address_space(3))) unsigned int*)(l), 16, 0, 0)

// ---------------- split conversion: fp32 -> bf16 hi + bf16 lo planes ----------------
__global__ __launch_bounds__(256) void cvt_split(const float* __restrict__ src,
                                                 us* __restrict__ hi, us* __restrict__ lo, int n)
{
    const int i = (blockIdx.x * 256 + threadIdx.x) * 8;
    if (i >= n) return;
    const float4 f0 = *(const float4*)&src[i];
    const float4 f1 = *(const float4*)&src[i + 4];
    const float v[8] = {f0.x, f0.y, f0.z, f0.w, f1.x, f1.y, f1.z, f1.w};
    us8 h, l;
#pragma unroll
    for (int j = 0; j < 8; ++j) {
        const us hh = bf16rne(v[j]);
        h[j] = hh;
        l[j] = bf16rne(v[j] - bf16tof(hh));
    }
    *(us8*)&hi[i] = h;
    *(us8*)&lo[i] = l;
}

// ---------------- split-bf16 MFMA GEMM ----------------
// C[M,N] = (Ahi+Alo)[M,K] * (Bhi+Blo)[N,K]^T + bias[N]
// = Ahi.Bhi + Ahi.Blo + Alo.Bhi  (lo*lo dropped, ~2^-16 relative)
// 128x128 tile, BK=32, 256 thr = 4 waves (2x2), 4x4 16x16 tiles per wave.
// LDS [row][k] unpadded (required by global_load_lds lane mapping), 64 B rows.
template <bool BF16_OUT>
__global__ __launch_bounds__(256) void gemm_split(
    const us* __restrict__ Ahi, const us* __restrict__ Alo,
    const us* __restrict__ Bhi, const us* __restrict__ Blo,
    const float* __restrict__ bias, void* __restrict__ Cout,
    int M, int N, int K)
{
    __shared__ __align__(16) us AsH[128 * 32];
    __shared__ __align__(16) us AsL[128 * 32];
    __shared__ __align__(16) us BsH[128 * 32];
    __shared__ __align__(16) us BsL[128 * 32];

    const int t    = threadIdx.x;
    const int lane = t & 63;
    const int w    = t >> 6;
    const int ml   = lane & 15;
    const int quad = lane >> 4;
    const int wm   = w >> 1;
    const int wn   = w & 1;

    const int m0 = blockIdx.y * 128;
    const int n0 = blockIdx.x * 128;

    // staging: wave w covers tile rows [w*32, w*32+32), 16 rows per inst
    const int srow = (lane >> 2);       // 0..15
    const int scol = (lane & 3) * 8;    // bf16 units, 16 B per lane

    const us* pAh = Ahi + (size_t)(m0 + w * 32 + srow) * K + scol;
    const us* pAl = Alo + (size_t)(m0 + w * 32 + srow) * K + scol;
    const us* pBh = Bhi + (size_t)(n0 + w * 32 + srow) * K + scol;
    const us* pBl = Blo + (size_t)(n0 + w * 32 + srow) * K + scol;
    const size_t rstep = (size_t)16 * K;

    us* lAh0 = &AsH[(w * 32) * 32];
    us* lAh1 = &AsH[(w * 32 + 16) * 32];
    us* lAl0 = &AsL[(w * 32) * 32];
    us* lAl1 = &AsL[(w * 32 + 16) * 32];
    us* lBh0 = &BsH[(w * 32) * 32];
    us* lBh1 = &BsH[(w * 32 + 16) * 32];
    us* lBl0 = &BsL[(w * 32) * 32];
    us* lBl1 = &BsL[(w * 32 + 16) * 32];

    f32x4 acc[4][4];
#pragma unroll
    for (int i = 0; i < 4; ++i)
#pragma unroll
        for (int j = 0; j < 4; ++j) {
            acc[i][j][0] = 0.f; acc[i][j][1] = 0.f; acc[i][j][2] = 0.f; acc[i][j][3] = 0.f;
        }

    for (int k0 = 0; k0 < K; k0 += 32) {
        __syncthreads();   // previous iteration done reading LDS
        GLL16(pAh + k0, lAh0); GLL16(pAh + k0 + rstep, lAh1);
        GLL16(pAl + k0, lAl0); GLL16(pAl + k0 + rstep, lAl1);
        GLL16(pBh + k0, lBh0); GLL16(pBh + k0 + rstep, lBh1);
        GLL16(pBl + k0, lBl0); GLL16(pBl + k0 + rstep, lBl1);
        __syncthreads();   // vmcnt(0) drain + barrier

        bf16x8 ah[4], al[4];
#pragma unroll
        for (int i = 0; i < 4; ++i) {
            ah[i] = __builtin_bit_cast(bf16x8, *(const us8*)&AsH[(wm * 64 + i * 16 + ml) * 32 + quad * 8]);
            al[i] = __builtin_bit_cast(bf16x8, *(const us8*)&AsL[(wm * 64 + i * 16 + ml) * 32 + quad * 8]);
        }
#pragma unroll
        for (int j = 0; j < 4; ++j) {
            const bf16x8 bh = __builtin_bit_cast(bf16x8, *(const us8*)&BsH[(wn * 64 + j * 16 + ml) * 32 + quad * 8]);
            const bf16x8 bl = __builtin_bit_cast(bf16x8, *(const us8*)&BsL[(wn * 64 + j * 16 + ml) * 32 + quad * 8]);
#pragma unroll
            for (int i = 0; i < 4; ++i) {
                acc[i][j] = __builtin_amdgcn_mfma_f32_16x16x32_bf16(ah[i], bh, acc[i][j], 0, 0, 0);
                acc[i][j] = __builtin_amdgcn_mfma_f32_16x16x32_bf16(ah[i], bl, acc[i][j], 0, 0, 0);
                acc[i][j] = __builtin_amdgcn_mfma_f32_16x16x32_bf16(al[i], bh, acc[i][j], 0, 0, 0);
            }
        }
    }

    // epilogue: C row = quad*4+r, col = ml (per 16x16 tile)
    float bj[4];
#pragma unroll
    for (int j = 0; j < 4; ++j) bj[j] = bias[n0 + wn * 64 + j * 16 + ml];

#pragma unroll
    for (int i = 0; i < 4; ++i) {
#pragma unroll
        for (int r = 0; r < 4; ++r) {
            const size_t rowoff = (size_t)(m0 + wm * 64 + i * 16 + quad * 4 + r) * N;
#pragma unroll
            for (int j = 0; j < 4; ++j) {
                const int col = n0 + wn * 64 + j * 16 + ml;
                const float v = acc[i][j][r] + bj[j];
                if (BF16_OUT) ((us*)Cout)[rowoff + col] = bf16rne(v);
                else          ((float*)Cout)[rowoff + col] = v;
            }
        }
    }
}

// ---------------- MFMA flash attention (bf16 qkv in, split-bf16 vals out) ----------------
#define AW  8
#define ABQ 128   // queries per block
#define ACH 64    // keys per chunk
#define LQ  72    // LDS row stride in bf16 elems

__global__ __launch_bounds__(512, 4) void attn_mfma(
    const us* __restrict__ qkvb, us* __restrict__ vHi, us* __restrict__ vLo)
{
    __shared__ __align__(16) us Qs[ABQ][LQ];
    __shared__ __align__(16) us Ks[ACH][LQ];
    __shared__ __align__(16) us Vt[HD][LQ];      // Vt[dim][key]
    __shared__ __align__(16) us Ps[AW][16][LQ];

    const int t    = threadIdx.x;
    const int lane = t & 63;
    const int w    = t >> 6;
    const int ml   = lane & 15;
    const int quad = lane >> 4;

    const int bh = blockIdx.y;
    const int b  = bh >> 4;
    const int h  = bh & 15;
    const int q0 = blockIdx.x * ABQ;

    const size_t base = (size_t)b * SLEN * E3;
    const int qoff = h * 192;

    // stage Q (128 q x 64 d), bf16 direct
    {
        const int row = t >> 2;
        const int seg = (t & 3) * 16;
        const us* g = &qkvb[base + (size_t)(q0 + row) * E3 + qoff + seg];
        *(us8*)&Qs[row][seg]     = *(const us8*)(g);
        *(us8*)&Qs[row][seg + 8] = *(const us8*)(g + 8);
    }

    float mrow[4], lrow[4];
    f32x4 O[4];
#pragma unroll
    for (int r = 0; r < 4; ++r) {
        mrow[r] = -INFINITY; lrow[r] = 0.f;
        O[r][0] = 0.f; O[r][1] = 0.f; O[r][2] = 0.f; O[r][3] = 0.f;
    }

    const float C = 0.125f;  // 1/sqrt(HD), folded into exp args
    const int krow = t >> 3;        // 0..63
    const int kseg = (t & 7) * 8;   // 0..56

    for (int c = 0; c < SLEN / ACH; ++c) {
        __syncthreads();
        {
            const us* gk = &qkvb[base + (size_t)(c * ACH + krow) * E3 + qoff + 64 + kseg];
            const us8 kv = *(const us8*)(gk);
            const us8 vv = *(const us8*)(gk + 64);
            *(us8*)&Ks[krow][kseg] = kv;
#pragma unroll
            for (int i = 0; i < 8; ++i) Vt[kseg + i][krow] = vv[i];
        }
        __syncthreads();

        // QK^T
        const bf16x8 aq0 = __builtin_bit_cast(bf16x8, *(const us8*)&Qs[w * 16 + ml][quad * 8]);
        const bf16x8 aq1 = __builtin_bit_cast(bf16x8, *(const us8*)&Qs[w * 16 + ml][32 + quad * 8]);
        f32x4 sc[4];
#pragma unroll
        for (int nt = 0; nt < 4; ++nt) {
            const bf16x8 bk0 = __builtin_bit_cast(bf16x8, *(const us8*)&Ks[nt * 16 + ml][quad * 8]);
            const bf16x8 bk1 = __builtin_bit_cast(bf16x8, *(const us8*)&Ks[nt * 16 + ml][32 + quad * 8]);
            f32x4 z = {0.f, 0.f, 0.f, 0.f};
            z = __builtin_amdgcn_mfma_f32_16x16x32_bf16(aq0, bk0, z, 0, 0, 0);
            z = __builtin_amdgcn_mfma_f32_16x16x32_bf16(aq1, bk1, z, 0, 0, 0);
            sc[nt] = z;
        }

        // online softmax
#pragma unroll
        for (int r = 0; r < 4; ++r) {
            float cm = fmaxf(fmaxf(sc[0][r], sc[1][r]), fmaxf(sc[2][r], sc[3][r]));
            cm = fmaxf(cm, __shfl_xor(cm, 1));
            cm = fmaxf(cm, __shfl_xor(cm, 2));
            cm = fmaxf(cm, __shfl_xor(cm, 4));
            cm = fmaxf(cm, __shfl_xor(cm, 8));
            const float mn = fmaxf(mrow[r], cm);
            const float alpha = __expf((mrow[r] - mn) * C);
            mrow[r] = mn;
            float ps = 0.f;
            unsigned short pb[4];
#pragma unroll
            for (int nt = 0; nt < 4; ++nt) {
                const float p = __expf((sc[nt][r] - mn) * C);
                ps += p;
                pb[nt] = bf16rne(p);
            }
            ps += __shfl_xor(ps, 1);
            ps += __shfl_xor(ps, 2);
            ps += __shfl_xor(ps, 4);
            ps += __shfl_xor(ps, 8);
            lrow[r] = lrow[r] * alpha + ps;
#pragma unroll
            for (int nt = 0; nt < 4; ++nt) {
                O[nt][r] *= alpha;
                Ps[w][quad * 4 + r][nt * 16 + ml] = pb[nt];
            }
        }

        // PV
        const bf16x8 ap0 = __builtin_bit_cast(bf16x8, *(const us8*)&Ps[w][ml][quad * 8]);
        const bf16x8 ap1 = __builtin_bit_cast(bf16x8, *(const us8*)&Ps[w][ml][32 + quad * 8]);
#pragma unroll
        for (int nt = 0; nt < 4; ++nt) {
            const bf16x8 bv0 = __builtin_bit_cast(bf16x8, *(const us8*)&Vt[nt * 16 + ml][quad * 8]);
            const bf16x8 bv1 = __builtin_bit_cast(bf16x8, *(const us8*)&Vt[nt * 16 + ml][32 + quad * 8]);
            O[nt] = __builtin_amdgcn_mfma_f32_16x16x32_bf16(ap0, bv0, O[nt], 0, 0, 0);
            O[nt] = __builtin_amdgcn_mfma_f32_16x16x32_bf16(ap1, bv1, O[nt], 0, 0, 0);
        }
    }

    // epilogue: normalize, split to hi/lo planes
#pragma unroll
    for (int r = 0; r < 4; ++r) {
        const float rl = 1.0f / lrow[r];
        const int q = q0 + w * 16 + quad * 4 + r;
#pragma unroll
        for (int nt = 0; nt < 4; ++nt) {
            const float o = O[nt][r] * rl;
            const us hi = bf16rne(o);
            const size_t idx = (size_t)(b * SLEN + q) * DMODEL + h * HD + nt * 16 + ml;
            vHi[idx] = hi;
            vLo[idx] = bf16rne(o - bf16tof(hi));
        }
    }
}

// ---------------- launch ----------------
extern "C" void kernel_launch(void* const* d_in, const int* in_sizes, int n_in,
                              void* d_out, int out_size, void* d_ws, size_t ws_size,
                              hipStream_t stream) {
    const float* x     = (const float*)d_in[0];
    const float* w_qkv = (const float*)d_in[1];
    const float* b_qkv = (const float*)d_in[2];
    const float* w_o   = (const float*)d_in[3];
    const float* b_o   = (const float*)d_in[4];
    float* out = (float*)d_out;

    const int M   = BATCH * SLEN;        // 4096
    const int XN  = M * DIN;             // 4,194,304
    const int WQN = E3 * DIN;            // 3,145,728
    const int WON = DMODEL * DMODEL;     // 1,048,576
    const size_t QKVN = (size_t)BATCH * SLEN * E3;  // 12,582,912

    // workspace regions (us units). Region X reused: x planes -> vals planes.
    // Region W reused: wqkv planes -> wo planes. Peak = 54.6 MB.
    us* qkvb = (us*)d_ws;                // [QKVN]
    us* xHi  = qkvb + QKVN;              // region X: [XN] + [XN]
    us* xLo  = xHi + XN;
    us* wHi  = xLo + XN;                 // region W: [WQN] + [WQN]
    us* wLo  = wHi + WQN;

    // 1) split-convert activations and qkv weights
    cvt_split<<<dim3(XN / 2048), 256, 0, stream>>>(x, xHi, xLo, XN);
    cvt_split<<<dim3(WQN / 2048), 256, 0, stream>>>(w_qkv, wHi, wLo, WQN);

    // 2) qkv = x @ w_qkv^T + b_qkv  -> bf16 [4096 x 3072]
    gemm_split<true><<<dim3(E3 / 128, M / 128), 256, 0, stream>>>(
        xHi, xLo, wHi, wLo, b_qkv, qkvb, M, E3, DIN);

    // 3) attention -> vals hi/lo planes (reuse region X; x is dead)
    us* vHi = xHi;
    us* vLo = xLo;
    attn_mfma<<<dim3(SLEN / ABQ, BATCH * NHEAD), 512, 0, stream>>>(qkvb, vHi, vLo);

    // 4) split-convert w_o (reuse region W; wqkv planes dead)
    us* woHi = wHi;
    us* woLo = wHi + WON;
    cvt_split<<<dim3(WON / 2048), 256, 0, stream>>>(w_o, woHi, woLo, WON);

    // 5) out = vals @ w_o^T + b_o  -> fp32 [4096 x 1024]
    gemm_split<false><<<dim3(DMODEL / 128, M / 128), 256, 0, stream>>>(
        vHi, vLo, woHi, woLo, b_o, out, M, DMODEL, DMODEL);
}